// Round 10
// baseline (2853.331 us; speedup 1.0000x reference)
//
#include <hip/hip_runtime.h>
#include <cstdint>
#include <cstddef>

#define NCLS 32000
#define EMBD 512
#define HIDD 1024
#define BATCH 64
#define SEQL 256
#define NWG 256
#define BH (BATCH * HIDD)          // 65536 elements
#define HBYTES (BH * 2)            // 131072 bytes per h buffer

// ---- tiled layout: buf[k/32][64 b][32 k] bf16 (4KB tiles, k-contiguous rows of 64B)

typedef __attribute__((ext_vector_type(8))) short short8;
typedef __attribute__((ext_vector_type(4))) float float4v;
typedef unsigned long long ull;
typedef unsigned short ushort;

// ---- workspace layout (bytes) ----
#define WS_CTR   0                           // 2048 B reserved
#define WS_H0G   2048                        // 2 buffers bf16 tiled
#define WS_H1G   (WS_H0G + 2*HBYTES)
#define WS_XEMB  (WS_H1G + 2*HBYTES)         // 16 MB, tiled per t

// ---- LDS: h0stage [31][2048] = 126976 B | red [8][64][16] f32 = 32768 B | meta 16 B
// xstage (4 xemb blocks, 16 KB) ALIASES red[4..7]: dead between L1-epi and part2.
#define LDS_RED_OFF  126976
#define LDS_XST_OFF  (126976 + 16384)
#define LDS_META_OFF (126976 + 32768)
#define SMEM_BYTES   (126976 + 32768 + 16)

__device__ __forceinline__ ushort f2bf(float f) {
  union { float f; uint32_t u; } x; x.f = f;
  uint32_t r = x.u + 0x7FFFu + ((x.u >> 16) & 1u);
  return (ushort)(r >> 16);
}

__device__ __forceinline__ float sigm(float x) {
  return 1.0f / (1.0f + __expf(-x));
}

// flat monotonic barrier (startup only) with deadlock watchdog
__device__ __forceinline__ void gbar(unsigned* bar, unsigned* gen, unsigned* dead,
                                     unsigned target) {
  __syncthreads();
  if (threadIdx.x == 0) {
    unsigned prev = __hip_atomic_fetch_add(bar, 1u, __ATOMIC_RELAXED, __HIP_MEMORY_SCOPE_AGENT);
    if (prev == target * NWG - 1u) {
      __hip_atomic_store(gen, target, __ATOMIC_RELAXED, __HIP_MEMORY_SCOPE_AGENT);
    } else {
      unsigned spin = 0;
      while (__hip_atomic_load(gen, __ATOMIC_RELAXED, __HIP_MEMORY_SCOPE_AGENT) < target) {
        if (__hip_atomic_load(dead, __ATOMIC_RELAXED, __HIP_MEMORY_SCOPE_AGENT) != 0u) break;
        if (++spin > 2000000u) {
          __hip_atomic_store(dead, 1u, __ATOMIC_RELAXED, __HIP_MEMORY_SCOPE_AGENT);
          break;
        }
        __builtin_amdgcn_s_sleep(1);
      }
    }
  }
  __syncthreads();
}

__global__ void init_bar_k(char* ws) {
  if (threadIdx.x < 320) ((unsigned*)(ws + WS_CTR))[threadIdx.x] = 0u;
}

// gather embeddings -> bf16 xemb, tiled [t][e/32][64 b][32 e]
__global__ void embed_k(const int* __restrict__ X, const float* __restrict__ Cemb,
                        char* __restrict__ ws) {
  uint32_t p = blockIdx.x * 256u + threadIdx.x;   // pair index
  uint32_t t = p >> 14;
  uint32_t r = p & 16383u;
  uint32_t b = r >> 8;
  uint32_t e2 = r & 255u;
  int row = X[b * SEQL + t];
  const float2 v = *(const float2*)(Cemb + (size_t)row * EMBD + (size_t)e2 * 2);
  uint32_t lo = f2bf(v.x), hi = f2bf(v.y);
  uint32_t dw = t * 16384u + (e2 >> 4) * 1024u + b * 16u + (e2 & 15u);
  ((uint32_t*)(ws + WS_XEMB))[dw] = (hi << 16) | lo;
}

__global__ __launch_bounds__(512, 1)
void lstm_k(const float* __restrict__ Wi0, const float* __restrict__ Wc0,
            const float* __restrict__ Wf0, const float* __restrict__ Wo0,
            const float* __restrict__ Wi1, const float* __restrict__ Wc1,
            const float* __restrict__ Wf1, const float* __restrict__ Wo1,
            const float* __restrict__ bi0, const float* __restrict__ bc0,
            const float* __restrict__ bf0, const float* __restrict__ bo0,
            const float* __restrict__ bi1, const float* __restrict__ bc1,
            const float* __restrict__ bf1, const float* __restrict__ bo1,
            char* ws) {
  const int wg   = blockIdx.x;
  const int tid  = threadIdx.x;
  const int lane = tid & 63;
  const int wv   = tid >> 6;        // 0..7
  const int l15  = lane & 15;
  const int quad = lane >> 4;

  extern __shared__ char smem[];
  ushort* h0st   = (ushort*)smem;                       // [31][2048] h0 stage (swizzled)
  float*  red    = (float*)(smem + LDS_RED_OFF);        // [8 waves][64 b][16 n]
  ushort* xstage = (ushort*)(smem + LDS_XST_OFF);       // [4][2048] xemb stage (aliases red[4..7])
  int*    meta   = (int*)(smem + LDS_META_OFF);         // [0]=nloc, [1]=nxcd

  ushort* h0buf = (ushort*)(ws + WS_H0G);
  ushort* h1buf = (ushort*)(ws + WS_H1G);
  const ushort* xemb = (const ushort*)(ws + WS_XEMB);
  unsigned* ctr = (unsigned*)(ws + WS_CTR);

  // XCD id (HW_REG_XCC_ID = hwreg 20) [measured: learn_hip m09]
  const unsigned xcc = __builtin_amdgcn_s_getreg((3u << 11) | 20u) & 7u;

  if (tid == 0)
    __hip_atomic_fetch_add(ctr + 32 + xcc, 1u, __ATOMIC_RELAXED, __HIP_MEMORY_SCOPE_AGENT);

  // ---- weight fragments -> VGPRs via LDS bounce (one-time) ----
  short8 bfr[16];
  {
    ushort* scr = (ushort*)smem;     // scratch overlaps h0stage (pre-loop only)
    {
      const float* W0g[4] = {Wi0, Wc0, Wf0, Wo0};
      int jl = tid & 3, kr = tid >> 2, jg = wg * 4 + jl;
      for (int g = 0; g < 4; ++g) {
        ushort* dst = scr + (jl * 4 + g) * 1536;
        const float* s = W0g[g] + jg;
        for (int k = kr; k < 1536; k += 128) dst[k] = f2bf(s[(size_t)k * HIDD]);
      }
    }
    __syncthreads();
    if (wv < 4) {
      #pragma unroll
      for (int j = 0; j < 12; ++j)
        bfr[j] = *(const short8*)(scr + l15 * 1536 + (12 * wv + j) * 32 + quad * 8);
    }
    __syncthreads();
    {
      const float* W1g[4] = {Wi1, Wc1, Wf1, Wo1};
      int jl = tid & 3, kr = tid >> 2, jg = wg * 4 + jl;
      for (int g = 0; g < 4; ++g) {
        ushort* dst = scr + (jl * 4 + g) * 2048;
        const float* s = W1g[g] + jg;
        for (int k = kr; k < 2048; k += 128) dst[k] = f2bf(s[(size_t)k * HIDD]);
      }
    }
    __syncthreads();
    if (wv >= 4) {
      #pragma unroll
      for (int j = 0; j < 8; ++j)
        bfr[j] = *(const short8*)(scr + l15 * 2048 + ((wv - 4) * 256 + j * 32) + quad * 8);
      #pragma unroll
      for (int j = 0; j < 8; ++j)
        bfr[8 + j] = *(const short8*)(scr + l15 * 2048 + 1024 + ((wv - 4) * 256 + j * 32) + quad * 8);
    }
    __syncthreads();
  }

  // ---- per-epilogue-thread bias + c-state in registers ----
  float bs0 = 0.f, bs1 = 0.f, bs2 = 0.f, bs3 = 0.f, cstr = 0.f;
  {
    int jl = tid & 3, jg = wg * 4 + jl;
    if (tid < 256) { bs0 = bi0[jg]; bs1 = bc0[jg]; bs2 = bf0[jg]; bs3 = bo0[jg]; }
    else           { bs0 = bi1[jg]; bs1 = bc1[jg]; bs2 = bf1[jg]; bs3 = bo1[jg]; }
  }

  if (tid < 128) {   // zero h state (buffer 0), tiled addressing
    ushort* base = (tid < 64) ? h0buf : h1buf;
    int b = tid & 63;
    __hip_atomic_store((ull*)(base + ((wg >> 3) << 11) + b * 32 + (wg & 7) * 4), 0ull,
                       __ATOMIC_RELAXED, __HIP_MEMORY_SCOPE_AGENT);
  }

  gbar(ctr + 48, ctr + 56, ctr + 17, 1u);

  if (tid == 0) {
    int nl = (int)__hip_atomic_load(ctr + 32 + xcc, __ATOMIC_RELAXED, __HIP_MEMORY_SCOPE_AGENT);
    int nx = 0;
    for (int x = 0; x < 8; ++x)
      nx += (__hip_atomic_load(ctr + 32 + x, __ATOMIC_RELAXED, __HIP_MEMORY_SCOPE_AGENT) != 0u);
    meta[0] = nl; meta[1] = nx;
  }
  __syncthreads();
  const unsigned nloc = (unsigned)meta[0], nxcd = (unsigned)meta[1];

  const int lofs = l15 * 32 + quad * 8;            // per-lane offset in a 2048-elem tile
  const int lswz = lofs ^ ((l15 & 7) * 8);         // bank-conflict-free stage addressing

  // pre-swizzled global source offset (ushorts) for xemb->LDS prefetch:
  // inverse of the lswz read mapping so linear global_load_lds writes land such
  // that reads at lswz return the correct elements. Derivation: m=lane;
  // l=(m5,m4,m3, m2^m4), q=(m1^m3, m0^m2^m4); sofs = l*32 + q*8.
  const int psw_l = ((lane >> 2) & 0xE) | (((lane >> 2) ^ (lane >> 4)) & 1);
  const int psw_q = ((((lane >> 1) ^ (lane >> 3)) & 1) << 1) |
                    ((lane ^ (lane >> 2) ^ (lane >> 4)) & 1);
  const int psofs = psw_l * 32 + psw_q * 8;

  unsigned tgt = 0;
  for (int p = 0; p <= SEQL; ++p) {
    const int run0 = (p < SEQL);
    const int run1 = (p >= 1);
    float4v acc0 = {0.f,0.f,0.f,0.f}, acc1 = acc0, acc2 = acc0, acc3 = acc0;

    // ================= part 1 =================
    if (wv < 4) {
      if (run0) {
        const ushort* hp = h0buf + (size_t)(p & 1) * BH;        // h0(p-1) tiled
        const ushort* xe = xemb + (size_t)p * BATCH * EMBD;     // x(p) tiled
        #pragma unroll
        for (int bb = 0; bb < 2; ++bb) {
          short8 d[6][4];
          #pragma unroll
          for (int i = 0; i < 6; ++i) {
            int kb = 12 * wv + bb * 6 + i;
            if (p >= 1 && kb >= 44) {          // xemb from LDS stage (prefetched)
              const ushort* sp = xstage + (kb - 44) * 2048 + lswz;
              d[i][0] = *(const short8*)(sp);
              d[i][1] = *(const short8*)(sp + 512);
              d[i][2] = *(const short8*)(sp + 1024);
              d[i][3] = *(const short8*)(sp + 1536);
            } else {
              const ushort* base = (kb < 32) ? (hp + kb * 2048) : (xe + (kb - 32) * 2048);
              const ushort* ab = base + lofs;
              d[i][0] = *(const short8*)(ab);
              d[i][1] = *(const short8*)(ab + 512);
              d[i][2] = *(const short8*)(ab + 1024);
              d[i][3] = *(const short8*)(ab + 1536);
            }
          }
          #pragma unroll
          for (int i = 0; i < 6; ++i) {
            int kb = 12 * wv + bb * 6 + i;
            if (kb <= 30) {           // stage h0 fragment for L1 (swizzled)
              ushort* sp = h0st + kb * 2048 + lswz;
              *(short8*)(sp)        = d[i][0];
              *(short8*)(sp + 512)  = d[i][1];
              *(short8*)(sp + 1024) = d[i][2];
              *(short8*)(sp + 1536) = d[i][3];
            }
            short8 w = bfr[bb * 6 + i];
            acc0 = __builtin_amdgcn_mfma_f32_16x16x32_bf16(d[i][0], w, acc0, 0, 0, 0);
            acc1 = __builtin_amdgcn_mfma_f32_16x16x32_bf16(d[i][1], w, acc1, 0, 0, 0);
            acc2 = __builtin_amdgcn_mfma_f32_16x16x32_bf16(d[i][2], w, acc2, 0, 0, 0);
            acc3 = __builtin_amdgcn_mfma_f32_16x16x32_bf16(d[i][3], w, acc3, 0, 0, 0);
          }
        }
        float* rw = red + wv * 1024 + quad * 64 + l15;
        #pragma unroll
        for (int r = 0; r < 4; ++r) {
          rw[r * 16]       = acc0[r];
          rw[256 + r * 16] = acc1[r];
          rw[512 + r * 16] = acc2[r];
          rw[768 + r * 16] = acc3[r];
        }
      }
    } else {
      if (run1) {   // h1p half (8 blocks, global)
        const ushort* h1p = h1buf + (size_t)((p & 1) ^ 1) * BH;  // h1(p-2)
        #pragma unroll
        for (int bb = 0; bb < 2; ++bb) {
          short8 d[4][4];
          #pragma unroll
          for (int i = 0; i < 4; ++i) {
            int kb = (wv - 4) * 8 + bb * 4 + i;
            const ushort* ab = h1p + kb * 2048 + lofs;
            d[i][0] = *(const short8*)(ab);
            d[i][1] = *(const short8*)(ab + 512);
            d[i][2] = *(const short8*)(ab + 1024);
            d[i][3] = *(const short8*)(ab + 1536);
          }
          #pragma unroll
          for (int i = 0; i < 4; ++i) {
            short8 w = bfr[bb * 4 + i];
            acc0 = __builtin_amdgcn_mfma_f32_16x16x32_bf16(d[i][0], w, acc0, 0, 0, 0);
            acc1 = __builtin_amdgcn_mfma_f32_16x16x32_bf16(d[i][1], w, acc1, 0, 0, 0);
            acc2 = __builtin_amdgcn_mfma_f32_16x16x32_bf16(d[i][2], w, acc2, 0, 0, 0);
            acc3 = __builtin_amdgcn_mfma_f32_16x16x32_bf16(d[i][3], w, acc3, 0, 0, 0);
          }
        }
      }
    }
    __syncthreads();   // A: h0stage complete; red[0..3] complete

    // ============ L0 epilogue (waves 0-3) overlaps part 2 (waves 4-7) ============
    if (run0 && tid < 256) {
      int b = tid >> 2;
      const float* rr = red + b * 16 + (tid & 3) * 4;
      float4v v = *(const float4v*)rr;
      v += *(const float4v*)(rr + 1024);
      v += *(const float4v*)(rr + 2048);
      v += *(const float4v*)(rr + 3072);
      float ig = sigm(v.x + bs0);
      float gg = tanhf(v.y + bs1);
      float fg = sigm(v.z + bs2);
      float og = sigm(v.w + bs3);
      float c = fg * cstr + ig * gg;
      cstr = c;
      unsigned x  = f2bf(og * tanhf(c));
      unsigned x1 = (unsigned)__shfl((int)x, lane + 1);
      unsigned x2 = (unsigned)__shfl((int)x, lane + 2);
      unsigned x3 = (unsigned)__shfl((int)x, lane + 3);
      if ((lane & 3) == 0) {
        ull val = (ull)(x | (x1 << 16)) | ((ull)(x2 | (x3 << 16)) << 32);
        ushort* dst = h0buf + (size_t)((p & 1) ^ 1) * BH
                    + ((wg >> 3) << 11) + b * 32 + (wg & 7) * 4;
        __hip_atomic_store((ull*)dst, val, __ATOMIC_RELAXED, __HIP_MEMORY_SCOPE_AGENT);
      }
    }
    if (run1 && wv >= 4) {   // part 2: h0c half (8 blocks, LDS when staged)
      const ushort* h0c = h0buf + (size_t)(p & 1) * BH;
      const bool useLds = (p < SEQL);
      #pragma unroll
      for (int bb = 0; bb < 2; ++bb) {
        short8 d[4][4];
        #pragma unroll
        for (int i = 0; i < 4; ++i) {
          int kb = (wv - 4) * 8 + bb * 4 + i;
          if (useLds && kb <= 30) {
            const ushort* sp = h0st + kb * 2048 + lswz;
            d[i][0] = *(const short8*)(sp);
            d[i][1] = *(const short8*)(sp + 512);
            d[i][2] = *(const short8*)(sp + 1024);
            d[i][3] = *(const short8*)(sp + 1536);
          } else {
            const ushort* ab = h0c + kb * 2048 + lofs;
            d[i][0] = *(const short8*)(ab);
            d[i][1] = *(const short8*)(ab + 512);
            d[i][2] = *(const short8*)(ab + 1024);
            d[i][3] = *(const short8*)(ab + 1536);
          }
        }
        #pragma unroll
        for (int i = 0; i < 4; ++i) {
          short8 w = bfr[8 + bb * 4 + i];
          acc0 = __builtin_amdgcn_mfma_f32_16x16x32_bf16(d[i][0], w, acc0, 0, 0, 0);
          acc1 = __builtin_amdgcn_mfma_f32_16x16x32_bf16(d[i][1], w, acc1, 0, 0, 0);
          acc2 = __builtin_amdgcn_mfma_f32_16x16x32_bf16(d[i][2], w, acc2, 0, 0, 0);
          acc3 = __builtin_amdgcn_mfma_f32_16x16x32_bf16(d[i][3], w, acc3, 0, 0, 0);
        }
      }
      float* rw = red + wv * 1024 + quad * 64 + l15;
      #pragma unroll
      for (int r = 0; r < 4; ++r) {
        rw[r * 16]       = acc0[r];
        rw[256 + r * 16] = acc1[r];
        rw[512 + r * 16] = acc2[r];
        rw[768 + r * 16] = acc3[r];
      }
    }
    __syncthreads();   // B: red[4..7] complete

    if (run1 && tid >= 256) {   // L1 epilogue
      int t = tid - 256, b = t >> 2;
      const float* rr = red + 4096 + b * 16 + (t & 3) * 4;
      float4v v = *(const float4v*)rr;
      v += *(const float4v*)(rr + 1024);
      v += *(const float4v*)(rr + 2048);
      v += *(const float4v*)(rr + 3072);
      float ig = sigm(v.x + bs0);
      float gg = tanhf(v.y + bs1);
      float fg = sigm(v.z + bs2);
      float og = sigm(v.w + bs3);
      float c = fg * cstr + ig * gg;
      cstr = c;
      unsigned x  = f2bf(og * tanhf(c));
      unsigned x1 = (unsigned)__shfl((int)x, lane + 1);
      unsigned x2 = (unsigned)__shfl((int)x, lane + 2);
      unsigned x3 = (unsigned)__shfl((int)x, lane + 3);
      if ((lane & 3) == 0) {
        ull val = (ull)(x | (x1 << 16)) | ((ull)(x2 | (x3 << 16)) << 32);
        ushort* dst = h1buf + (size_t)(p & 1) * BH
                    + ((wg >> 3) << 11) + b * 32 + (wg & 7) * 4;
        __hip_atomic_store((ull*)dst, val, __ATOMIC_RELAXED, __HIP_MEMORY_SCOPE_AGENT);
      }
    }
    if (p == SEQL) break;

    // ---- barrier: publishes drained -> arrive; buffer_inv overlapped with the
    // global release poll; xemb(p+1) prefetch to LDS overlapped with everything.
    __syncthreads();           // drains publishes (all waves); red[4..7] reads done
    if (p < SEQL - 1) {        // prefetch xemb(p+1) blocks 12..15 into xstage
      const ushort* xn = xemb + (size_t)(p + 1) * BATCH * EMBD;
      #pragma unroll
      for (int s = 0; s < 2; ++s) {
        int i = wv * 2 + s;
        int j = 12 + (i >> 2), q = i & 3;
        __builtin_amdgcn_global_load_lds(
            (const unsigned int*)(xn + j * 2048 + q * 512 + psofs),
            (unsigned int*)(xstage + (j - 12) * 2048 + q * 512),
            16, 0, 0);
      }
    }
    ++tgt;
    if (tid == 0) {
      unsigned* xctr = ctr + 64 + 16 * xcc;
      unsigned* xgen = ctr + 192 + 16 * xcc;
      unsigned* dead = ctr + 17;
      unsigned a = __hip_atomic_fetch_add(xctr, 1u, __ATOMIC_RELAXED, __HIP_MEMORY_SCOPE_AGENT);
      if (a == tgt * nloc - 1u) {          // last arriver on this XCD
        unsigned g = __hip_atomic_fetch_add(ctr, 1u, __ATOMIC_RELAXED, __HIP_MEMORY_SCOPE_AGENT);
        asm volatile("buffer_inv sc1" ::: "memory");   // issue; completion checked below
        if (g == tgt * nxcd - 1u) {
          __hip_atomic_store(ctr + 16, tgt, __ATOMIC_RELAXED, __HIP_MEMORY_SCOPE_AGENT);
        } else {
          unsigned spin = 0;
          while (__hip_atomic_load(ctr + 16, __ATOMIC_RELAXED, __HIP_MEMORY_SCOPE_AGENT) < tgt) {
            if ((++spin & 63u) == 0u) {
              if (__hip_atomic_load(dead, __ATOMIC_RELAXED, __HIP_MEMORY_SCOPE_AGENT) != 0u) break;
              if (spin > 4000000u) {
                __hip_atomic_store(dead, 1u, __ATOMIC_RELAXED, __HIP_MEMORY_SCOPE_AGENT);
                break;
              }
            }
          }
        }
        asm volatile("s_waitcnt vmcnt(0)" ::: "memory");   // inv (and polls) complete
        __hip_atomic_store(xgen, tgt, __ATOMIC_RELAXED, __HIP_MEMORY_SCOPE_AGENT);
      } else {
        unsigned spin = 0;
        while (__hip_atomic_load(xgen, __ATOMIC_RELAXED, __HIP_MEMORY_SCOPE_AGENT) < tgt) {
          if ((++spin & 63u) == 0u) {
            if (__hip_atomic_load(dead, __ATOMIC_RELAXED, __HIP_MEMORY_SCOPE_AGENT) != 0u) break;
            if (spin > 4000000u) {
              __hip_atomic_store(dead, 1u, __ATOMIC_RELAXED, __HIP_MEMORY_SCOPE_AGENT);
              break;
            }
          }
        }
      }
    }
    __syncthreads();   // release + prefetch drained
  }
}

// logits via MFMA: out[b][n] = sum_k h1[b][k] * Wout[k][n] + bout[n]
__global__ __launch_bounds__(256, 1)
void out_gemm_k(const char* __restrict__ ws, const float* __restrict__ Wout,
                const float* __restrict__ bout, float* __restrict__ out) {
  const ushort* h1 = (const ushort*)(ws + WS_H1G);  // bf16 tiled, buf 0
  const int tid = threadIdx.x, lane = tid & 63, wv = tid >> 6;
  const int l15 = lane & 15, quad = lane >> 4;
  const int n0 = blockIdx.x * 128 + wv * 32;
  float4v acc[4][2];
  #pragma unroll
  for (int m = 0; m < 4; ++m)
    #pragma unroll
    for (int f = 0; f < 2; ++f) acc[m][f] = (float4v){0.f, 0.f, 0.f, 0.f};

  for (int k0 = 0; k0 < HIDD; k0 += 32) {
    const ushort* tb = h1 + ((k0 >> 5) << 11) + l15 * 32 + quad * 8;
    short8 a[4];
    #pragma unroll
    for (int m = 0; m < 4; ++m)
      a[m] = *(const short8*)(tb + m * 512);
    short8 bf[2];
    #pragma unroll
    for (int f = 0; f < 2; ++f) {
      int n = n0 + f * 16 + l15;
      #pragma unroll
      for (int j = 0; j < 8; ++j) {
        float w = Wout[(size_t)(k0 + quad * 8 + j) * NCLS + n];
        bf[f][j] = (short)f2bf(w);
      }
    }
    #pragma unroll
    for (int m = 0; m < 4; ++m)
      #pragma unroll
      for (int f = 0; f < 2; ++f)
        acc[m][f] = __builtin_amdgcn_mfma_f32_16x16x32_bf16(a[m], bf[f], acc[m][f], 0, 0, 0);
  }
  #pragma unroll
  for (int m = 0; m < 4; ++m)
    #pragma unroll
    for (int f = 0; f < 2; ++f) {
      int n = n0 + f * 16 + l15;
      float bb = bout[n];
      #pragma unroll
      for (int r = 0; r < 4; ++r) {
        int b = m * 16 + quad * 4 + r;
        out[(size_t)b * NCLS + n] = acc[m][f][r] + bb;
      }
    }
}

extern "C" void kernel_launch(void* const* d_in, const int* in_sizes, int n_in,
                              void* d_out, int out_size, void* d_ws, size_t ws_size,
                              hipStream_t stream) {
  const int*   X    = (const int*)d_in[0];
  const float* Cemb = (const float*)d_in[1];
  const float* Wi0  = (const float*)d_in[2];
  const float* bi0  = (const float*)d_in[3];
  const float* Wc0  = (const float*)d_in[4];
  const float* bc0  = (const float*)d_in[5];
  const float* Wf0  = (const float*)d_in[6];
  const float* bf0  = (const float*)d_in[7];
  const float* Wo0  = (const float*)d_in[8];
  const float* bo0  = (const float*)d_in[9];
  const float* Wi1  = (const float*)d_in[10];
  const float* bi1  = (const float*)d_in[11];
  const float* Wc1  = (const float*)d_in[12];
  const float* bc1  = (const float*)d_in[13];
  const float* Wf1  = (const float*)d_in[14];
  const float* bf1  = (const float*)d_in[15];
  const float* Wo1  = (const float*)d_in[16];
  const float* bo1  = (const float*)d_in[17];
  const float* Wout = (const float*)d_in[18];
  const float* bout = (const float*)d_in[19];
  float* out = (float*)d_out;
  char* ws = (char*)d_ws;

  hipFuncSetAttribute((const void*)lstm_k,
                      hipFuncAttributeMaxDynamicSharedMemorySize, SMEM_BYTES);

  init_bar_k<<<1, 512, 0, stream>>>(ws);
  embed_k<<<16384, 256, 0, stream>>>(X, Cemb, ws);
  lstm_k<<<NWG, 512, SMEM_BYTES, stream>>>(Wi0, Wc0, Wf0, Wo0, Wi1, Wc1, Wf1, Wo1,
                                           bi0, bc0, bf0, bo0, bi1, bc1, bf1, bo1, ws);
  out_gemm_k<<<250, 256, 0, stream>>>(ws, Wout, bout, out);
}